// Round 4
// baseline (1049.308 us; speedup 1.0000x reference)
//
#include <hip/hip_runtime.h>

typedef short short8  __attribute__((ext_vector_type(8)));
typedef short short4v __attribute__((ext_vector_type(4)));
typedef float f32x4   __attribute__((ext_vector_type(4)));

#define B_   2
#define T_   2048
#define D_   4096
#define N_   32
#define KH_  8
#define H_   128
#define BT_  (B_*T_)
#define NH_  (N_*H_)
#define NTK  64          // K tiles of 64 (K = 4096 for both GEMMs)

__device__ __forceinline__ short f2bf(float f) {
    unsigned u = __float_as_uint(f);
    u += 0x7fffu + ((u >> 16) & 1u);
    return (short)(u >> 16);
}

// global -> LDS async 16B copy; LDS dest = wave-uniform base + lane*16
__device__ __forceinline__ void gl_lds16(const short* g, short* l) {
    __builtin_amdgcn_global_load_lds(
        (const __attribute__((address_space(1))) void*)(g),
        (__attribute__((address_space(3))) void*)(l), 16, 0, 0);
}

// ---------------------------------------------------------------------------
// x fp32 -> bf16 flat cast
// ---------------------------------------------------------------------------
__global__ __launch_bounds__(256) void cast_x_kernel(const float* __restrict__ in,
                                                     short* __restrict__ out) {
    const size_t i = ((size_t)blockIdx.x * 256 + threadIdx.x) * 8;
    float4 v0 = *reinterpret_cast<const float4*>(in + i);
    float4 v1 = *reinterpret_cast<const float4*>(in + i + 4);
    short8 s;
    s[0] = f2bf(v0.x); s[1] = f2bf(v0.y); s[2] = f2bf(v0.z); s[3] = f2bf(v0.w);
    s[4] = f2bf(v1.x); s[5] = f2bf(v1.y); s[6] = f2bf(v1.z); s[7] = f2bf(v1.w);
    *reinterpret_cast<short8*>(out + i) = s;
}

// ---------------------------------------------------------------------------
// Transpose + cast: in (R,C) fp32 slices -> out (C,R) bf16 slices
// ---------------------------------------------------------------------------
__global__ void transpose_cast_kernel(const float* __restrict__ in,
                                      short* __restrict__ out, int R, int C) {
    __shared__ float tile[32][33];
    const long long slice = blockIdx.z;
    in  += slice * (long long)R * C;
    out += slice * (long long)R * C;
    const int c0 = blockIdx.x * 32, r0 = blockIdx.y * 32;
    const int tx = threadIdx.x, ty = threadIdx.y;
#pragma unroll
    for (int i = 0; i < 4; i++) {
        int r = r0 + ty + i * 8;
        tile[ty + i * 8][tx] = in[(long long)r * C + c0 + tx];
    }
    __syncthreads();
#pragma unroll
    for (int i = 0; i < 4; i++) {
        int cc = c0 + ty + i * 8;
        out[(long long)cc * R + r0 + tx] = f2bf(tile[tx][ty + i * 8]);
    }
}

// ===========================================================================
// GEMM core: BM=256, BN=128, BK=64, 512 threads (8 waves as 4M x 2N),
// per-wave 64x64 output. 3 LDS buffers x 3 units (A0,A1,B) of 128x64 bf16
// = 144 KiB. Stage tile t+2 while computing tile t (2-tile pipeline depth).
// ONE barrier + ONE counted vmcnt(6) per K-tile (3 distinct buffers -> no
// intra-tile LDS hazard; buf (t+2)%3's last readers finished before tile
// (t-1)'s end barrier, which precedes tile t's stage issues).
// XOR-atom LDS swizzle; inverse-swizzled global source (linear gl_lds dest).
// ===========================================================================

#define RA(cb, jm) {                                                            \
    const int rr_ = arl + (jm) * 16 + l15;                                      \
    a[jm][0] = *reinterpret_cast<const short8*>(&lds[cb][au][rr_ * 64 + at0]);  \
    a[jm][1] = *reinterpret_cast<const short8*>(&lds[cb][au][rr_ * 64 + at1]); }

#define RB(cb, jn) {                                                            \
    const int rb_ = ((jn) >> 1) * 64 + wc * 32 + ((jn) & 1) * 16 + l15;         \
    b[jn][0] = *reinterpret_cast<const short8*>(&lds[cb][2][rb_ * 64 + at0]);   \
    b[jn][1] = *reinterpret_cast<const short8*>(&lds[cb][2][rb_ * 64 + at1]); }

#define STG(G, grow, sb, un, kt_) {                                             \
    int ktc_ = (kt_); if (ktc_ > NTK - 1) ktc_ = NTK - 1;                       \
    const short* gs_ = (G) + (size_t)((grow) + srow) * 4096 + ktc_ * 64 + sca * 8; \
    gl_lds16(gs_,            &lds[sb][un][(2 * w) * 512]);                      \
    gl_lds16(gs_ + 8 * 4096, &lds[sb][un][(2 * w) * 512 + 512]); }

#define MG(JM0, JN0)                                                            \
    __builtin_amdgcn_s_setprio(1);                                              \
    _Pragma("unroll")                                                           \
    for (int jm_ = 0; jm_ < 2; ++jm_)                                           \
    _Pragma("unroll")                                                           \
    for (int jn_ = 0; jn_ < 2; ++jn_)                                           \
    _Pragma("unroll")                                                           \
    for (int ks_ = 0; ks_ < 2; ++ks_)                                           \
        acc[(JM0) + jm_][(JN0) + jn_] = __builtin_amdgcn_mfma_f32_16x16x32_bf16( \
            a[(JM0) + jm_][ks_], b[(JN0) + jn_][ks_], acc[(JM0) + jm_][(JN0) + jn_], 0, 0, 0); \
    __builtin_amdgcn_s_setprio(0);

#define GCORE(Ap, Bp, M0, N0)                                                   \
    f32x4 acc[4][4];                                                            \
    { const f32x4 z_ = {0.f, 0.f, 0.f, 0.f};                                    \
      _Pragma("unroll") for (int i_ = 0; i_ < 4; ++i_)                          \
      _Pragma("unroll") for (int j_ = 0; j_ < 4; ++j_) acc[i_][j_] = z_; }      \
    short8 a[4][2], b[4][2];                                                    \
    STG(Ap, (M0),       0, 0, 0); STG(Ap, (M0) + 128, 0, 1, 0);                 \
    STG(Bp, (N0),       0, 2, 0);                                               \
    STG(Ap, (M0),       1, 0, 1); STG(Ap, (M0) + 128, 1, 1, 1);                 \
    STG(Bp, (N0),       1, 2, 1);                                               \
    asm volatile("s_waitcnt vmcnt(6)" ::: "memory");                            \
    __builtin_amdgcn_s_barrier();                                               \
    for (int t = 0; t < NTK; ++t) {                                             \
        const int cb = t % 3, pb = (t + 2) % 3;                                 \
        RA(cb, 0); RA(cb, 1); RB(cb, 0); RB(cb, 1);                             \
        STG(Ap, (M0), pb, 0, t + 2);                                            \
        MG(0, 0);                                                               \
        RA(cb, 2); RA(cb, 3);                                                   \
        STG(Ap, (M0) + 128, pb, 1, t + 2);                                      \
        MG(2, 0);                                                               \
        RB(cb, 2); RB(cb, 3);                                                   \
        STG(Bp, (N0), pb, 2, t + 2);                                            \
        MG(2, 2);                                                               \
        MG(0, 2);                                                               \
        asm volatile("s_waitcnt vmcnt(6)" ::: "memory");                        \
        __builtin_amdgcn_s_barrier();                                           \
    }                                                                           \
    asm volatile("s_waitcnt vmcnt(0)" ::: "memory");

#define GEMM_PREAMBLE                                                           \
    const int tid = threadIdx.x;                                                \
    const int w = tid >> 6, lane = tid & 63;                                    \
    const int quad = lane >> 4, l15 = lane & 15;                                \
    const int wr = w >> 1, wc = w & 1;                                          \
    const int au = wr >> 1;                                                     \
    const int arl = (wr & 1) * 64;                                              \
    const int sw = l15 & 7;                                                     \
    const int at0 = (quad ^ sw) * 8;                                            \
    const int at1 = ((4 + quad) ^ sw) * 8;                                      \
    const int srow = 16 * w + (lane >> 3);                                      \
    const int sca = (lane & 7) ^ (lane >> 3);

// ---------------------------------------------------------------------------
// QKV projection GEMM. B-matrix = [wqt|wkvt] contiguous (6144 x 4096 bf16).
// BN=128 -> one head per block; RoPE pairs (h, h+64) in-wave via split cols:
// h(jn) = (jn>=2)*64 + wc*32 + (jn&1)*16 + l15.
// Grid 768 = 3 x 256 CUs exactly (no tail). Bijective XCD swizzle.
// ---------------------------------------------------------------------------
__global__ __launch_bounds__(512, 2) void qkv_gemm8_kernel(
    const short* __restrict__ xb, const int* __restrict__ positions,
    const short* __restrict__ wqt,
    short* __restrict__ qo, short* __restrict__ ko, short* __restrict__ vto)
{
    __shared__ short lds[3][3][8192];
    GEMM_PREAMBLE
    const int bid = blockIdx.x;
    const int swz = (bid & 7) * 96 + (bid >> 3);     // 768 = 8*96, bijective
    const int mt = swz / 48, nt = swz - mt * 48;     // n fast: 2 A-panels/XCD
    const int m0 = mt * 256, n0 = nt * 128;

    GCORE(xb, wqt, m0, n0)

    const int head = nt;
    if (head < 40) {
        // q or k: RoPE; q pre-scaled by H^-0.5 * log2e (fixed-max softmax)
        const float qs = (head < 32) ? (0.08838834764831845f * 1.4426950408889634f) : 1.0f;
#pragma unroll
        for (int jm = 0; jm < 4; ++jm) {
#pragma unroll
            for (int reg = 0; reg < 4; ++reg) {
                const int bt = m0 + wr * 64 + jm * 16 + quad * 4 + reg;
                const int bb = bt >> 11, t = bt & (T_ - 1);
                short* dst = (head < 32)
                    ? qo + ((size_t)(bb * N_ + head) * T_ + t) * H_
                    : ko + ((size_t)(bb * KH_ + (head - 32)) * T_ + t) * H_;
                const float pos = (float)positions[bt];
#pragma unroll
                for (int j = 0; j < 2; ++j) {
                    const int h2 = wc * 32 + j * 16 + l15;
                    float inv_ts = exp2f((float)h2 * -0.20762050593048935f); // log2(10000)/64
                    float rev = pos * inv_ts * 0.15915494309189535f;
                    rev -= floorf(rev);
                    float sn, cs;
                    __sincosf(rev * 6.283185307179586f, &sn, &cs);
                    float x1 = acc[jm][j][reg], x2 = acc[jm][j + 2][reg];
                    dst[h2]      = f2bf((x1 * cs - x2 * sn) * qs);
                    dst[h2 + 64] = f2bf((x2 * cs + x1 * sn) * qs);
                }
            }
        }
    } else {
        // v: store transposed (B,KH,H,T)
        const int vh = head - 40;
        const int bb = m0 >> 11;
        const int tl0 = (m0 & (T_ - 1)) + wr * 64;
#pragma unroll
        for (int jm = 0; jm < 4; ++jm) {
            const int t0r = tl0 + jm * 16 + quad * 4;
#pragma unroll
            for (int jn = 0; jn < 4; ++jn) {
                const int h = (jn >> 1) * 64 + wc * 32 + (jn & 1) * 16 + l15;
                short4v pv;
                pv[0] = f2bf(acc[jm][jn][0]); pv[1] = f2bf(acc[jm][jn][1]);
                pv[2] = f2bf(acc[jm][jn][2]); pv[3] = f2bf(acc[jm][jn][3]);
                *reinterpret_cast<short4v*>(vto + ((size_t)(bb * KH_ + vh) * H_ + h) * T_ + t0r) = pv;
            }
        }
    }
}

// ---------------------------------------------------------------------------
// Output projection GEMM: out(BT,D) = enc(BT,NH) @ wot^T. Grid 512 = 2 x 256.
// ---------------------------------------------------------------------------
__global__ __launch_bounds__(512, 2) void out_gemm8_kernel(
    const short* __restrict__ enc, const short* __restrict__ wot,
    float* __restrict__ out)
{
    __shared__ short lds[3][3][8192];
    GEMM_PREAMBLE
    const int bid = blockIdx.x;
    const int swz = (bid & 7) * 64 + (bid >> 3);     // 512 = 8*64, bijective
    const int mt = swz >> 5, nt = swz & 31;
    const int m0 = mt * 256, n0 = nt * 128;

    GCORE(enc, wot, m0, n0)

#pragma unroll
    for (int jm = 0; jm < 4; ++jm)
#pragma unroll
        for (int jn = 0; jn < 4; ++jn) {
            const int col = n0 + (jn >> 1) * 64 + wc * 32 + (jn & 1) * 16 + l15;
#pragma unroll
            for (int reg = 0; reg < 4; ++reg) {
                const int r = m0 + wr * 64 + jm * 16 + quad * 4 + reg;
                out[(size_t)r * D_ + col] = acc[jm][jn][reg];
            }
        }
}

// ---------------------------------------------------------------------------
// Barrier-free flash attention, S^T formulation, 32-s strips, s-SPLIT pairs.
// Task = t-tile pair {63-pr, pr} (65 strips). Each task is split across TWO
// waves (even/odd strips) -> 4096 uniform waves, 4 waves/SIMD (VGPR<=128).
// Fixed-max exp2 softmax => partials combine by addition: sub1 wave writes
// its partial O (f32) + lsum into the pair's (dead) P buffers; sub0 adds,
// normalizes, stores.
// ---------------------------------------------------------------------------
__global__ __launch_bounds__(256, 4) void attn_kernel(
    const short* __restrict__ qp, const short* __restrict__ kp,
    const short* __restrict__ vtp, short* __restrict__ encp)
{
    __shared__ __align__(16) short ldsP[4][32 * 128];
    __shared__ float ldsL[2][2][64];
    const int tid = threadIdx.x;
    const int w = tid >> 6, lane = tid & 63;
    const int quad = lane >> 4, l15 = lane & 15;
    const int pairi = w >> 1, sub = w & 1;
    const int widx2 = blockIdx.x * 2 + pairi;      // 2048 tasks
    const int pr = widx2 & 31;
    const int n  = (widx2 >> 5) & 31;
    const int b  = widx2 >> 10;
    const int kh = n >> 2;
    short* P = ldsP[w];
    float* OC = reinterpret_cast<float*>(&ldsP[2 * pairi][0]);  // 16KB combine

    const short* qbase = qp  + (size_t)(b * N_  + n)  * T_ * H_;
    const short* kbase = kp  + (size_t)(b * KH_ + kh) * T_ * H_;
    const short* vbase = vtp + (size_t)(b * KH_ + kh) * H_ * T_;

    const f32x4 zero4 = {0.f, 0.f, 0.f, 0.f};

    for (int half = 0; half < 2; half++) {
        const int wt = half ? pr : (63 - pr);   // t-tile index; strips = wt+1
        const int t0 = wt * 32;

        // Q^T B-frags, stationary: [k=h=32ks+8quad+j][n=t=16jc+l15]
        short8 qf[2][4];
#pragma unroll
        for (int jc = 0; jc < 2; jc++)
#pragma unroll
            for (int ks = 0; ks < 4; ks++)
                qf[jc][ks] = *reinterpret_cast<const short8*>(
                    qbase + (size_t)(t0 + 16 * jc + l15) * H_ + ks * 32 + quad * 8);

        f32x4 o[2][8];     // O[m=t: 16jm+4quad+reg][n=h: 16jn+l15]
#pragma unroll
        for (int jm = 0; jm < 2; jm++)
#pragma unroll
            for (int jn = 0; jn < 8; jn++) o[jm][jn] = zero4;
        float lsum[2] = {0.f, 0.f};

        for (int ss = sub; ss <= wt; ss += 2) {
            const int s0 = ss * 32;
            const int slot = ((ss >> 1) & 3) * 4;   // 16B-atom slot base in P

            // V^T frags for this strip
            short8 vb[8];
#pragma unroll
            for (int jn = 0; jn < 8; jn++)
                vb[jn] = *reinterpret_cast<const short8*>(
                    vbase + (size_t)(16 * jn + l15) * T_ + s0 + quad * 8);

            // S^T: A=K[m=s=16jr+l15][k=h], B=Q^T
            f32x4 s[2][2];
#pragma unroll
            for (int jr = 0; jr < 2; jr++)
#pragma unroll
                for (int jc = 0; jc < 2; jc++) s[jr][jc] = zero4;
#pragma unroll
            for (int ks = 0; ks < 4; ks++) {
                short8 kb[2];
#pragma unroll
                for (int jr = 0; jr < 2; jr++)
                    kb[jr] = *reinterpret_cast<const short8*>(
                        kbase + (size_t)(s0 + 16 * jr + l15) * H_ + ks * 32 + quad * 8);
#pragma unroll
                for (int jr = 0; jr < 2; jr++)
#pragma unroll
                    for (int jc = 0; jc < 2; jc++)
                        s[jr][jc] = __builtin_amdgcn_mfma_f32_16x16x32_bf16(kb[jr], qf[jc][ks], s[jr][jc], 0, 0, 0);
            }

            if (ss == wt) {  // diagonal strip: mask s_local > t_local
#pragma unroll
                for (int jr = 0; jr < 2; jr++)
#pragma unroll
                    for (int jc = 0; jc < 2; jc++)
#pragma unroll
                        for (int reg = 0; reg < 4; reg++) {
                            int sl = 16 * jr + 4 * quad + reg;
                            int tl = 16 * jc + l15;
                            if (sl > tl) s[jr][jc][reg] = -1.0e30f;
                        }
            }

            // p = exp2(s), accumulate l, pack 4 consecutive s -> ds_write_b64
#pragma unroll
            for (int jr = 0; jr < 2; jr++)
#pragma unroll
                for (int jc = 0; jc < 2; jc++) {
                    short4v pk;
#pragma unroll
                    for (int reg = 0; reg < 4; reg++) {
                        float p = exp2f(s[jr][jc][reg]);
                        lsum[jc] += p;
                        pk[reg] = f2bf(p);
                    }
                    const int row = 16 * jc + l15;                       // t_local
                    const int cc  = slot + 2 * jr + (quad >> 1);         // 16B atom
                    const int hf  = quad & 1;                            // 8B half
                    *reinterpret_cast<short4v*>(
                        &P[row * 128 + ((cc ^ l15) << 3) + (hf << 2)]) = pk;
                }
            asm volatile("s_waitcnt lgkmcnt(0)" ::: "memory");

            // O += P·V : A=P[m=t=16jm+l15][k=s_local=8quad+j], B=vb
#pragma unroll
            for (int jm = 0; jm < 2; jm++) {
                short8 pa = *reinterpret_cast<const short8*>(
                    &P[(16 * jm + l15) * 128 + (((slot + quad) ^ l15) << 3)]);
#pragma unroll
                for (int jn = 0; jn < 8; jn++)
                    o[jm][jn] = __builtin_amdgcn_mfma_f32_16x16x32_bf16(pa, vb[jn], o[jm][jn], 0, 0, 0);
            }
        }

        // --- pair combine: sub1 -> LDS, sub0 adds, normalizes, stores ---
        __syncthreads();
        if (sub == 1) {
#pragma unroll
            for (int jm = 0; jm < 2; jm++)
#pragma unroll
                for (int jn = 0; jn < 8; jn++)
                    *reinterpret_cast<f32x4*>(&OC[((jm * 8 + jn) * 64 + lane) * 4]) = o[jm][jn];
            ldsL[pairi][0][lane] = lsum[0];
            ldsL[pairi][1][lane] = lsum[1];
        }
        __syncthreads();
        if (sub == 0) {
#pragma unroll
            for (int jm = 0; jm < 2; jm++)
#pragma unroll
                for (int jn = 0; jn < 8; jn++) {
                    f32x4 t = *reinterpret_cast<const f32x4*>(&OC[((jm * 8 + jn) * 64 + lane) * 4]);
                    o[jm][jn] += t;
                }
            lsum[0] += ldsL[pairi][0][lane];
            lsum[1] += ldsL[pairi][1][lane];

            // full l = quad-reduce; route to O's lane mapping; store bf16
#pragma unroll
            for (int jc = 0; jc < 2; jc++) {
                lsum[jc] += __shfl_xor(lsum[jc], 16, 64);
                lsum[jc] += __shfl_xor(lsum[jc], 32, 64);
            }
#pragma unroll
            for (int jm = 0; jm < 2; jm++)
#pragma unroll
                for (int reg = 0; reg < 4; reg++) {
                    const float inv = 1.0f / __shfl(lsum[jm], 4 * quad + reg, 64);
                    const int t = t0 + 16 * jm + 4 * quad + reg;
                    const size_t base = (size_t)(b * T_ + t) * NH_ + n * H_;
#pragma unroll
                    for (int jn = 0; jn < 8; jn++)
                        encp[base + 16 * jn + l15] = f2bf(o[jm][jn][reg] * inv);
                }
        }
        __syncthreads();   // protect OC (aliases P) before next half's strips
    }
}

// ---------------------------------------------------------------------------
extern "C" void kernel_launch(void* const* d_in, const int* in_sizes, int n_in,
                              void* d_out, int out_size, void* d_ws, size_t ws_size,
                              hipStream_t stream)
{
    const float* x         = (const float*)d_in[0];
    const int*   positions = (const int*)d_in[1];
    const float* wq        = (const float*)d_in[3];
    const float* wkv       = (const float*)d_in[4];
    const float* wo        = (const float*)d_in[5];
    float* out = (float*)d_out;

    char* ws = (char*)d_ws;
    short* wqt  = (short*)(ws);                 // 33,554,432 B  (wkvt contiguous after)
    short* wkvt = (short*)(ws + 33554432);      // 16,777,216 B
    short* q    = (short*)(ws + 50331648);      // 33,554,432 B
    short* kx   = (short*)(ws + 83886080);      //  8,388,608 B
    short* vt   = (short*)(ws + 92274688);      //  8,388,608 B
    short* xbf  = (short*)(ws + 100663296);     // 33,554,432 B
    short* wot  = (short*)(ws + 100663296);     // alias of xbf
    short* enc  = (short*)(ws);                 // alias of wqt

    dim3 tb(32, 8);
    cast_x_kernel<<<dim3((BT_ * (size_t)D_) / 2048), dim3(256), 0, stream>>>(x, xbf);
    transpose_cast_kernel<<<dim3(H_/32, D_/32, N_),    tb, 0, stream>>>(wq,  wqt,  D_,  H_);
    transpose_cast_kernel<<<dim3(H_/32, D_/32, 2*KH_), tb, 0, stream>>>(wkv, wkvt, D_,  H_);

    // BM=256, BN=128: grid 16m x 48n = 768 = 3 x 256 CUs exactly
    qkv_gemm8_kernel<<<dim3(768), dim3(512), 0, stream>>>(xbf, positions, wqt, q, kx, vt);

    transpose_cast_kernel<<<dim3(D_/32, NH_/32, 1),    tb, 0, stream>>>(wo,  wot,  NH_, D_);

    // 2048 tasks s-split across 4096 waves in 1024 blocks (4 waves/SIMD)
    attn_kernel<<<dim3(1024), dim3(256), 0, stream>>>(q, kx, vt, enc);

    // grid 16m x 32n = 512 = 2 x 256 CUs exactly
    out_gemm8_kernel<<<dim3(512), dim3(512), 0, stream>>>(enc, wot, out);
}

// Round 5
// 804.083 us; speedup vs baseline: 1.3050x; 1.3050x over previous
//
#include <hip/hip_runtime.h>

typedef short short8  __attribute__((ext_vector_type(8)));
typedef short short4v __attribute__((ext_vector_type(4)));
typedef float f32x4   __attribute__((ext_vector_type(4)));

#define B_   2
#define T_   2048
#define D_   4096
#define N_   32
#define KH_  8
#define H_   128
#define BT_  (B_*T_)
#define NH_  (N_*H_)
#define NTK  64          // K tiles of 64 (K = 4096 for both GEMMs)

__device__ __forceinline__ short f2bf(float f) {
    unsigned u = __float_as_uint(f);
    u += 0x7fffu + ((u >> 16) & 1u);
    return (short)(u >> 16);
}

// global -> LDS async 16B copy; LDS dest = wave-uniform base + lane*16
__device__ __forceinline__ void gl_lds16(const short* g, short* l) {
    __builtin_amdgcn_global_load_lds(
        (const __attribute__((address_space(1))) void*)(g),
        (__attribute__((address_space(3))) void*)(l), 16, 0, 0);
}

// ---------------------------------------------------------------------------
// x fp32 -> bf16 flat cast
// ---------------------------------------------------------------------------
__global__ __launch_bounds__(256) void cast_x_kernel(const float* __restrict__ in,
                                                     short* __restrict__ out) {
    const size_t i = ((size_t)blockIdx.x * 256 + threadIdx.x) * 8;
    float4 v0 = *reinterpret_cast<const float4*>(in + i);
    float4 v1 = *reinterpret_cast<const float4*>(in + i + 4);
    short8 s;
    s[0] = f2bf(v0.x); s[1] = f2bf(v0.y); s[2] = f2bf(v0.z); s[3] = f2bf(v0.w);
    s[4] = f2bf(v1.x); s[5] = f2bf(v1.y); s[6] = f2bf(v1.z); s[7] = f2bf(v1.w);
    *reinterpret_cast<short8*>(out + i) = s;
}

// ---------------------------------------------------------------------------
// Transpose + cast: in (R,C) fp32 slices -> out (C,R) bf16 slices
// ---------------------------------------------------------------------------
__global__ void transpose_cast_kernel(const float* __restrict__ in,
                                      short* __restrict__ out, int R, int C) {
    __shared__ float tile[32][33];
    const long long slice = blockIdx.z;
    in  += slice * (long long)R * C;
    out += slice * (long long)R * C;
    const int c0 = blockIdx.x * 32, r0 = blockIdx.y * 32;
    const int tx = threadIdx.x, ty = threadIdx.y;
#pragma unroll
    for (int i = 0; i < 4; i++) {
        int r = r0 + ty + i * 8;
        tile[ty + i * 8][tx] = in[(long long)r * C + c0 + tx];
    }
    __syncthreads();
#pragma unroll
    for (int i = 0; i < 4; i++) {
        int cc = c0 + ty + i * 8;
        out[(long long)cc * R + r0 + tx] = f2bf(tile[tx][ty + i * 8]);
    }
}

// ===========================================================================
// GEMM core: BM=256, BN=128, BK=64, 512 threads (8 waves as 4M x 2N),
// per-wave 64x64 output. 3 LDS buffers x 3 units (A0,A1,B) of 128x64 bf16
// = 144 KiB. Stage tile t+2 while computing tile t (2-tile pipeline depth).
// PER-PHASE barriers (4 phases/tile, m196/m201 fine-interleave pattern):
//   P1: vmcnt(6); bar; RA01+RB01; stage A0(t+2); MFMA Q1(jm01 x jn01)
//   P2: bar; RA23;                stage A1(t+2); MFMA Q2(jm23 x jn01)
//   P3: bar; RB23;                stage B (t+2); MFMA Q3(jm23 x jn23)
//   P4: bar;                                     MFMA Q4(jm01 x jn23)
// Counted vmcnt(6) once per tile (6 loads in flight = next tile's units);
// never vmcnt(0) in-loop. Hazard: stage into buf (t+2)%3 issues only after
// P1's barrier, which follows every wave's completion of tile t-1's reads
// (all reads precede t-1's P4 barrier).
// XOR-atom LDS swizzle; inverse-swizzled global source (linear gl_lds dest).
// ===========================================================================

#define RA(cb, jm) {                                                            \
    const int rr_ = arl + (jm) * 16 + l15;                                      \
    a[jm][0] = *reinterpret_cast<const short8*>(&lds[cb][au][rr_ * 64 + at0]);  \
    a[jm][1] = *reinterpret_cast<const short8*>(&lds[cb][au][rr_ * 64 + at1]); }

#define RB(cb, jn) {                                                            \
    const int rb_ = ((jn) >> 1) * 64 + wc * 32 + ((jn) & 1) * 16 + l15;         \
    b[jn][0] = *reinterpret_cast<const short8*>(&lds[cb][2][rb_ * 64 + at0]);   \
    b[jn][1] = *reinterpret_cast<const short8*>(&lds[cb][2][rb_ * 64 + at1]); }

#define STG(G, grow, sb, un, kt_) {                                             \
    int ktc_ = (kt_); if (ktc_ > NTK - 1) ktc_ = NTK - 1;                       \
    const short* gs_ = (G) + (size_t)((grow) + srow) * 4096 + ktc_ * 64 + sca * 8; \
    gl_lds16(gs_,            &lds[sb][un][(2 * w) * 512]);                      \
    gl_lds16(gs_ + 8 * 4096, &lds[sb][un][(2 * w) * 512 + 512]); }

#define MG(JM0, JN0)                                                            \
    __builtin_amdgcn_s_setprio(1);                                              \
    _Pragma("unroll")                                                           \
    for (int jm_ = 0; jm_ < 2; ++jm_)                                           \
    _Pragma("unroll")                                                           \
    for (int jn_ = 0; jn_ < 2; ++jn_)                                           \
    _Pragma("unroll")                                                           \
    for (int ks_ = 0; ks_ < 2; ++ks_)                                           \
        acc[(JM0) + jm_][(JN0) + jn_] = __builtin_amdgcn_mfma_f32_16x16x32_bf16( \
            a[(JM0) + jm_][ks_], b[(JN0) + jn_][ks_], acc[(JM0) + jm_][(JN0) + jn_], 0, 0, 0); \
    __builtin_amdgcn_s_setprio(0);

#define GCORE(Ap, Bp, M0, N0)                                                   \
    f32x4 acc[4][4];                                                            \
    { const f32x4 z_ = {0.f, 0.f, 0.f, 0.f};                                    \
      _Pragma("unroll") for (int i_ = 0; i_ < 4; ++i_)                          \
      _Pragma("unroll") for (int j_ = 0; j_ < 4; ++j_) acc[i_][j_] = z_; }      \
    short8 a[4][2], b[4][2];                                                    \
    STG(Ap, (M0),       0, 0, 0); STG(Ap, (M0) + 128, 0, 1, 0);                 \
    STG(Bp, (N0),       0, 2, 0);                                               \
    STG(Ap, (M0),       1, 0, 1); STG(Ap, (M0) + 128, 1, 1, 1);                 \
    STG(Bp, (N0),       1, 2, 1);                                               \
    for (int t = 0; t < NTK; ++t) {                                             \
        const int cb = t % 3, pb = (t + 2) % 3;                                 \
        /* P1 */                                                                \
        asm volatile("s_waitcnt vmcnt(6)" ::: "memory");                        \
        __builtin_amdgcn_s_barrier();                                           \
        RA(cb, 0); RA(cb, 1); RB(cb, 0); RB(cb, 1);                             \
        STG(Ap, (M0), pb, 0, t + 2);                                            \
        MG(0, 0);                                                               \
        /* P2 */                                                                \
        __builtin_amdgcn_s_barrier();                                           \
        RA(cb, 2); RA(cb, 3);                                                   \
        STG(Ap, (M0) + 128, pb, 1, t + 2);                                      \
        MG(2, 0);                                                               \
        /* P3 */                                                                \
        __builtin_amdgcn_s_barrier();                                           \
        RB(cb, 2); RB(cb, 3);                                                   \
        STG(Bp, (N0), pb, 2, t + 2);                                            \
        MG(2, 2);                                                               \
        /* P4 */                                                                \
        __builtin_amdgcn_s_barrier();                                           \
        MG(0, 2);                                                               \
    }                                                                           \
    asm volatile("s_waitcnt vmcnt(0)" ::: "memory");

#define GEMM_PREAMBLE                                                           \
    const int tid = threadIdx.x;                                                \
    const int w = tid >> 6, lane = tid & 63;                                    \
    const int quad = lane >> 4, l15 = lane & 15;                                \
    const int wr = w >> 1, wc = w & 1;                                          \
    const int au = wr >> 1;                                                     \
    const int arl = (wr & 1) * 64;                                              \
    const int sw = l15 & 7;                                                     \
    const int at0 = (quad ^ sw) * 8;                                            \
    const int at1 = ((4 + quad) ^ sw) * 8;                                      \
    const int srow = 16 * w + (lane >> 3);                                      \
    const int sca = (lane & 7) ^ (lane >> 3);

// ---------------------------------------------------------------------------
// QKV projection GEMM. B-matrix = [wqt|wkvt] contiguous (6144 x 4096 bf16).
// BN=128 -> one head per block; RoPE pairs (h, h+64) in-wave via split cols:
// h(jn) = (jn>=2)*64 + wc*32 + (jn&1)*16 + l15.
// Grid 768 = 3 x 256 CUs exactly (no tail). Bijective XCD swizzle.
// ---------------------------------------------------------------------------
__global__ __launch_bounds__(512, 2) void qkv_gemm8_kernel(
    const short* __restrict__ xb, const int* __restrict__ positions,
    const short* __restrict__ wqt,
    short* __restrict__ qo, short* __restrict__ ko, short* __restrict__ vto)
{
    __shared__ short lds[3][3][8192];
    GEMM_PREAMBLE
    const int bid = blockIdx.x;
    const int swz = (bid & 7) * 96 + (bid >> 3);     // 768 = 8*96, bijective
    const int mt = swz / 48, nt = swz - mt * 48;     // n fast: 2 A-panels/XCD
    const int m0 = mt * 256, n0 = nt * 128;

    GCORE(xb, wqt, m0, n0)

    const int head = nt;
    if (head < 40) {
        // q or k: RoPE; q pre-scaled by H^-0.5 * log2e (fixed-max softmax)
        const float qs = (head < 32) ? (0.08838834764831845f * 1.4426950408889634f) : 1.0f;
#pragma unroll
        for (int jm = 0; jm < 4; ++jm) {
#pragma unroll
            for (int reg = 0; reg < 4; ++reg) {
                const int bt = m0 + wr * 64 + jm * 16 + quad * 4 + reg;
                const int bb = bt >> 11, t = bt & (T_ - 1);
                short* dst = (head < 32)
                    ? qo + ((size_t)(bb * N_ + head) * T_ + t) * H_
                    : ko + ((size_t)(bb * KH_ + (head - 32)) * T_ + t) * H_;
                const float pos = (float)positions[bt];
#pragma unroll
                for (int j = 0; j < 2; ++j) {
                    const int h2 = wc * 32 + j * 16 + l15;
                    float inv_ts = exp2f((float)h2 * -0.20762050593048935f); // log2(10000)/64
                    float rev = pos * inv_ts * 0.15915494309189535f;
                    rev -= floorf(rev);
                    float sn, cs;
                    __sincosf(rev * 6.283185307179586f, &sn, &cs);
                    float x1 = acc[jm][j][reg], x2 = acc[jm][j + 2][reg];
                    dst[h2]      = f2bf((x1 * cs - x2 * sn) * qs);
                    dst[h2 + 64] = f2bf((x2 * cs + x1 * sn) * qs);
                }
            }
        }
    } else {
        // v: store transposed (B,KH,H,T)
        const int vh = head - 40;
        const int bb = m0 >> 11;
        const int tl0 = (m0 & (T_ - 1)) + wr * 64;
#pragma unroll
        for (int jm = 0; jm < 4; ++jm) {
            const int t0r = tl0 + jm * 16 + quad * 4;
#pragma unroll
            for (int jn = 0; jn < 4; ++jn) {
                const int h = (jn >> 1) * 64 + wc * 32 + (jn & 1) * 16 + l15;
                short4v pv;
                pv[0] = f2bf(acc[jm][jn][0]); pv[1] = f2bf(acc[jm][jn][1]);
                pv[2] = f2bf(acc[jm][jn][2]); pv[3] = f2bf(acc[jm][jn][3]);
                *reinterpret_cast<short4v*>(vto + ((size_t)(bb * KH_ + vh) * H_ + h) * T_ + t0r) = pv;
            }
        }
    }
}

// ---------------------------------------------------------------------------
// Output projection GEMM: out(BT,D) = enc(BT,NH) @ wot^T. Grid 512 = 2 x 256.
// ---------------------------------------------------------------------------
__global__ __launch_bounds__(512, 2) void out_gemm8_kernel(
    const short* __restrict__ enc, const short* __restrict__ wot,
    float* __restrict__ out)
{
    __shared__ short lds[3][3][8192];
    GEMM_PREAMBLE
    const int bid = blockIdx.x;
    const int swz = (bid & 7) * 64 + (bid >> 3);     // 512 = 8*64, bijective
    const int mt = swz >> 5, nt = swz & 31;
    const int m0 = mt * 256, n0 = nt * 128;

    GCORE(enc, wot, m0, n0)

#pragma unroll
    for (int jm = 0; jm < 4; ++jm)
#pragma unroll
        for (int jn = 0; jn < 4; ++jn) {
            const int col = n0 + (jn >> 1) * 64 + wc * 32 + (jn & 1) * 16 + l15;
#pragma unroll
            for (int reg = 0; reg < 4; ++reg) {
                const int r = m0 + wr * 64 + jm * 16 + quad * 4 + reg;
                out[(size_t)r * D_ + col] = acc[jm][jn][reg];
            }
        }
}

// ---------------------------------------------------------------------------
// Barrier-free flash attention, S^T formulation, 32-s strips. (round-2
// version, measured 252 us / VGPR 152 — REVERTED from the spilling s-split.)
// Causal pairing: each wave processes t-tiles {63-pr, pr} sequentially ->
// exactly 65 strips per wave, perfectly uniform across waves/CUs/XCDs.
// Cross-strip register prefetch: K[ss+1] issued after QK(ss), V[ss+1] after
// PV(ss). LDS: per-wave private 32x128 P buffer (8KB), 16B-atom XOR swizzle.
// ---------------------------------------------------------------------------
__global__ __launch_bounds__(256) void attn_kernel(
    const short* __restrict__ qp, const short* __restrict__ kp,
    const short* __restrict__ vtp, short* __restrict__ encp)
{
    __shared__ short ldsP[4 * 32 * 128];
    const int tid = threadIdx.x;
    const int w = tid >> 6, lane = tid & 63;
    const int quad = lane >> 4, l15 = lane & 15;
    const int widx = blockIdx.x * 4 + w;
    const int pr = widx & 31;          // pair index: tiles {63-pr, pr}
    const int n  = (widx >> 5) & 31;
    const int b  = widx >> 10;
    const int kh = n >> 2;
    short* P = ldsP + w * (32 * 128);

    const short* qbase = qp  + (size_t)(b * N_  + n)  * T_ * H_;
    const short* kbase = kp  + (size_t)(b * KH_ + kh) * T_ * H_;
    const short* vbase = vtp + (size_t)(b * KH_ + kh) * H_ * T_;

    const f32x4 zero4 = {0.f, 0.f, 0.f, 0.f};

    for (int half = 0; half < 2; half++) {
        const int wt = half ? pr : (63 - pr);   // t-tile index; strips = wt+1
        const int t0 = wt * 32;

        // Q^T B-frags, stationary: [k=h=32ks+8quad+j][n=t=16jc+l15]
        short8 qf[2][4];
#pragma unroll
        for (int jc = 0; jc < 2; jc++)
#pragma unroll
            for (int ks = 0; ks < 4; ks++)
                qf[jc][ks] = *reinterpret_cast<const short8*>(
                    qbase + (size_t)(t0 + 16 * jc + l15) * H_ + ks * 32 + quad * 8);

        f32x4 o[2][8];     // O[m=t: 16jm+4quad+reg][n=h: 16jn+l15]
#pragma unroll
        for (int jm = 0; jm < 2; jm++)
#pragma unroll
            for (int jn = 0; jn < 8; jn++) o[jm][jn] = zero4;
        float lsum[2] = {0.f, 0.f};   // l(t), t = 16jc + l15 (partial over quad's s)

        // prologue: preload K/V for strip 0
        short8 kb[8];   // [2*ks+jr]
        short8 vb[8];
#pragma unroll
        for (int jn = 0; jn < 8; jn++)
            vb[jn] = *reinterpret_cast<const short8*>(
                vbase + (size_t)(16 * jn + l15) * T_ + quad * 8);
#pragma unroll
        for (int ks = 0; ks < 4; ks++)
#pragma unroll
            for (int jr = 0; jr < 2; jr++)
                kb[2 * ks + jr] = *reinterpret_cast<const short8*>(
                    kbase + (size_t)(16 * jr + l15) * H_ + ks * 32 + quad * 8);

        for (int ss = 0; ss <= wt; ss++) {
            const int s0 = ss * 32;
            const int slot = (ss & 3) * 4;   // 16B-atom slot base in P (cycles 4 strips)
            const int s0n = (ss < wt) ? s0 + 32 : 0;   // clamped prefetch strip

            // S^T: A=K[m=s=16jr+l15][k=h], B=Q^T  (K in registers from prefetch)
            f32x4 s[2][2];
#pragma unroll
            for (int jr = 0; jr < 2; jr++)
#pragma unroll
                for (int jc = 0; jc < 2; jc++) s[jr][jc] = zero4;
#pragma unroll
            for (int ks = 0; ks < 4; ks++)
#pragma unroll
                for (int jr = 0; jr < 2; jr++)
#pragma unroll
                    for (int jc = 0; jc < 2; jc++)
                        s[jr][jc] = __builtin_amdgcn_mfma_f32_16x16x32_bf16(kb[2 * ks + jr], qf[jc][ks], s[jr][jc], 0, 0, 0);

            // prefetch next strip's K (latency hides under exp2 + LDS + PV)
#pragma unroll
            for (int ks = 0; ks < 4; ks++)
#pragma unroll
                for (int jr = 0; jr < 2; jr++)
                    kb[2 * ks + jr] = *reinterpret_cast<const short8*>(
                        kbase + (size_t)(s0n + 16 * jr + l15) * H_ + ks * 32 + quad * 8);

            if (ss == wt) {  // diagonal strip: mask s_local > t_local
#pragma unroll
                for (int jr = 0; jr < 2; jr++)
#pragma unroll
                    for (int jc = 0; jc < 2; jc++)
#pragma unroll
                        for (int reg = 0; reg < 4; reg++) {
                            int sl = 16 * jr + 4 * quad + reg;
                            int tl = 16 * jc + l15;
                            if (sl > tl) s[jr][jc][reg] = -1.0e30f;
                        }
            }

            // p = exp2(s), accumulate l, pack 4 consecutive s -> ds_write_b64
#pragma unroll
            for (int jr = 0; jr < 2; jr++)
#pragma unroll
                for (int jc = 0; jc < 2; jc++) {
                    short4v pk;
#pragma unroll
                    for (int reg = 0; reg < 4; reg++) {
                        float p = exp2f(s[jr][jc][reg]);
                        lsum[jc] += p;
                        pk[reg] = f2bf(p);
                    }
                    const int row = 16 * jc + l15;                       // t_local
                    const int cc  = slot + 2 * jr + (quad >> 1);         // 16B atom
                    const int hf  = quad & 1;                            // 8B half
                    *reinterpret_cast<short4v*>(
                        &P[row * 128 + ((cc ^ l15) << 3) + (hf << 2)]) = pk;
                }
            asm volatile("s_waitcnt lgkmcnt(0)" ::: "memory");

            // O += P·V : A=P[m=t=16jm+l15][k=s_local=8quad+j], B=vb
#pragma unroll
            for (int jm = 0; jm < 2; jm++) {
                short8 pa = *reinterpret_cast<const short8*>(
                    &P[(16 * jm + l15) * 128 + (((slot + quad) ^ l15) << 3)]);
#pragma unroll
                for (int jn = 0; jn < 8; jn++)
                    o[jm][jn] = __builtin_amdgcn_mfma_f32_16x16x32_bf16(pa, vb[jn], o[jm][jn], 0, 0, 0);
            }

            // prefetch next strip's V (latency hides under next QK + exp2)
#pragma unroll
            for (int jn = 0; jn < 8; jn++)
                vb[jn] = *reinterpret_cast<const short8*>(
                    vbase + (size_t)(16 * jn + l15) * T_ + s0n + quad * 8);
        }

        // epilogue: full l = quad-reduce; route to O's lane mapping; store bf16
#pragma unroll
        for (int jc = 0; jc < 2; jc++) {
            lsum[jc] += __shfl_xor(lsum[jc], 16, 64);
            lsum[jc] += __shfl_xor(lsum[jc], 32, 64);
        }
#pragma unroll
        for (int jm = 0; jm < 2; jm++)
#pragma unroll
            for (int reg = 0; reg < 4; reg++) {
                const float inv = 1.0f / __shfl(lsum[jm], 4 * quad + reg, 64);
                const int t = t0 + 16 * jm + 4 * quad + reg;
                const size_t base = (size_t)(b * T_ + t) * NH_ + n * H_;
#pragma unroll
                for (int jn = 0; jn < 8; jn++)
                    encp[base + 16 * jn + l15] = f2bf(o[jm][jn][reg] * inv);
            }
    }
}

// ---------------------------------------------------------------------------
extern "C" void kernel_launch(void* const* d_in, const int* in_sizes, int n_in,
                              void* d_out, int out_size, void* d_ws, size_t ws_size,
                              hipStream_t stream)
{
    const float* x         = (const float*)d_in[0];
    const int*   positions = (const int*)d_in[1];
    const float* wq        = (const float*)d_in[3];
    const float* wkv       = (const float*)d_in[4];
    const float* wo        = (const float*)d_in[5];
    float* out = (float*)d_out;

    char* ws = (char*)d_ws;
    short* wqt  = (short*)(ws);                 // 33,554,432 B  (wkvt contiguous after)
    short* wkvt = (short*)(ws + 33554432);      // 16,777,216 B
    short* q    = (short*)(ws + 50331648);      // 33,554,432 B
    short* kx   = (short*)(ws + 83886080);      //  8,388,608 B
    short* vt   = (short*)(ws + 92274688);      //  8,388,608 B
    short* xbf  = (short*)(ws + 100663296);     // 33,554,432 B
    short* wot  = (short*)(ws + 100663296);     // alias of xbf
    short* enc  = (short*)(ws);                 // alias of wqt

    dim3 tb(32, 8);
    cast_x_kernel<<<dim3((BT_ * (size_t)D_) / 2048), dim3(256), 0, stream>>>(x, xbf);
    transpose_cast_kernel<<<dim3(H_/32, D_/32, N_),    tb, 0, stream>>>(wq,  wqt,  D_,  H_);
    transpose_cast_kernel<<<dim3(H_/32, D_/32, 2*KH_), tb, 0, stream>>>(wkv, wkvt, D_,  H_);

    // BM=256, BN=128: grid 16m x 48n = 768 = 3 x 256 CUs exactly
    qkv_gemm8_kernel<<<dim3(768), dim3(512), 0, stream>>>(xbf, positions, wqt, q, kx, vt);

    transpose_cast_kernel<<<dim3(D_/32, NH_/32, 1),    tb, 0, stream>>>(wo,  wot,  NH_, D_);

    // 2048 uniform waves (65 strips each) in 512 blocks
    attn_kernel<<<dim3(512), dim3(256), 0, stream>>>(q, kx, vt, enc);

    // grid 16m x 32n = 512 = 2 x 256 CUs exactly
    out_gemm8_kernel<<<dim3(512), dim3(512), 0, stream>>>(enc, wot, out);
}